// Round 1
// baseline (472.029 us; speedup 1.0000x reference)
//
#include <hip/hip_runtime.h>
#include <hip/hip_bf16.h>
#include <stdint.h>

#define N 4096
#define BM 128
#define BN 128
#define BK 64

typedef __hip_bfloat16 bf16;
typedef __attribute__((ext_vector_type(8))) __bf16 bfrag;   // 8 bf16 = 4 VGPRs (MFMA A/B operand)
typedef __attribute__((ext_vector_type(4))) float floatx4;  // MFMA C/D operand

// ---------------------------------------------------------------------------
// async global -> LDS, 16B per lane (global_load_lds_dwordx4)
// LDS dest must be wave-uniform base + lane*16 -- our slot layout guarantees it.
// ---------------------------------------------------------------------------
__device__ __forceinline__ void gld_lds16(const void* g, void* l) {
    __builtin_amdgcn_global_load_lds(
        (const __attribute__((address_space(1))) void*)g,
        (__attribute__((address_space(3))) void*)l, 16, 0, 0);
}

// ---------------------------------------------------------------------------
// Kernel 1: out_bf16 = bf16(in_f32 * 1/64)   (fold the 1/sqrt(D) scale here)
// ---------------------------------------------------------------------------
__global__ __launch_bounds__(256) void cvt_scale(const float* __restrict__ in,
                                                 unsigned short* __restrict__ out) {
    const long i = ((long)blockIdx.x * 256 + threadIdx.x) * 8;
    float4 a = *(const float4*)(in + i);
    float4 b = *(const float4*)(in + i + 4);
    const float sc = 0.015625f;  // 1/64 = 1/sqrt(4096)
    float v[8] = {a.x, a.y, a.z, a.w, b.x, b.y, b.z, b.w};
    alignas(16) unsigned short r[8];
#pragma unroll
    for (int k = 0; k < 8; ++k) {
        __hip_bfloat16 h = __float2bfloat16(v[k] * sc);
        r[k] = *(unsigned short*)&h;
    }
    *(uint4*)(out + i) = *(const uint4*)r;
}

// ---------------------------------------------------------------------------
// Kernel 2/4: C[M,N] = A * B^T   (A: [M,K] bf16 row-major, B: [N,K] bf16
// row-major, C fp32 row-major). m97 structure: 128x128 block tile, BK=64,
// 4 waves each owning a 64x64 sub-tile (4x4 grid of 16x16x32 MFMAs),
// global_load_lds width=16 staging, 2-barrier K-loop.
// ---------------------------------------------------------------------------
__global__ __launch_bounds__(256) void gemm_bt(const bf16* __restrict__ A,
                                               const bf16* __restrict__ B,
                                               float* __restrict__ C) {
    __shared__ bf16 As[BM * BK];  // 16 KB, row-major [128][64], no padding
    __shared__ bf16 Bs[BN * BK];  // 16 KB

    const int t    = threadIdx.x;
    const int lane = t & 63;
    const int wave = t >> 6;      // 0..3
    const int wm   = wave >> 1;   // wave row 0..1
    const int wn   = wave & 1;    // wave col 0..1
    const int bm   = blockIdx.y * BM;
    const int bn   = blockIdx.x * BN;

    floatx4 acc[4][4] = {};

    // staging: slot s = i*256 + t; row = s>>3, kblk = s&7 (16B each)
    const bf16* Ag = A + (long)(bm + (t >> 3)) * N + (t & 7) * 8;
    const bf16* Bg = B + (long)(bn + (t >> 3)) * N + (t & 7) * 8;
    bf16* Asl = As + t * 8;
    bf16* Bsl = Bs + t * 8;

    for (int k0 = 0; k0 < N; k0 += BK) {
#pragma unroll
        for (int i = 0; i < 4; ++i) {
            gld_lds16(Ag + (long)i * 32 * N + k0, Asl + i * 2048);
            gld_lds16(Bg + (long)i * 32 * N + k0, Bsl + i * 2048);
        }
        __syncthreads();  // compiler emits s_waitcnt vmcnt(0) before s_barrier

#pragma unroll
        for (int kk = 0; kk < BK; kk += 32) {
            const int ko = kk + (lane >> 4) * 8;  // A[m][k]: m=lane&15, k=quad*8+j
            bfrag a[4], b[4];
#pragma unroll
            for (int i = 0; i < 4; ++i)
                a[i] = *(const bfrag*)&As[(wm * 64 + i * 16 + (lane & 15)) * BK + ko];
#pragma unroll
            for (int j = 0; j < 4; ++j)
                b[j] = *(const bfrag*)&Bs[(wn * 64 + j * 16 + (lane & 15)) * BK + ko];
#pragma unroll
            for (int i = 0; i < 4; ++i)
#pragma unroll
                for (int j = 0; j < 4; ++j)
                    acc[i][j] = __builtin_amdgcn_mfma_f32_16x16x32_bf16(
                        a[i], b[j], acc[i][j], 0, 0, 0);
        }
        __syncthreads();
    }

    // epilogue: C/D layout col=lane&15, row=(lane>>4)*4+reg  [m89-verified]
    const int col0 = bn + wn * 64 + (lane & 15);
    const int row0 = bm + wm * 64 + (lane >> 4) * 4;
#pragma unroll
    for (int i = 0; i < 4; ++i)
#pragma unroll
        for (int j = 0; j < 4; ++j)
#pragma unroll
            for (int r = 0; r < 4; ++r)
                C[(long)(row0 + i * 16 + r) * N + col0 + j * 16] = acc[i][j][r];
}

// ---------------------------------------------------------------------------
// Kernel 3: row softmax with diagonal mask; fp32 in -> bf16 probabilities out.
// One 256-thread block per row; 16 elements/thread kept in registers.
// ---------------------------------------------------------------------------
__global__ __launch_bounds__(256) void softmax_rows(const float* __restrict__ S,
                                                    unsigned short* __restrict__ P) {
    const int row = blockIdx.x;
    const float* s = S + (long)row * N;
    __shared__ float redmax[4];
    __shared__ float redsum[4];

    float vals[16];
    float m = -INFINITY;
#pragma unroll
    for (int k = 0; k < 16; ++k) {
        const int c = threadIdx.x + k * 256;
        float v = s[c];
        if (c == row) v = -INFINITY;  // mask self-similarity
        vals[k] = v;
        m = fmaxf(m, v);
    }
#pragma unroll
    for (int off = 32; off >= 1; off >>= 1) m = fmaxf(m, __shfl_xor(m, off));
    if ((threadIdx.x & 63) == 0) redmax[threadIdx.x >> 6] = m;
    __syncthreads();
    m = fmaxf(fmaxf(redmax[0], redmax[1]), fmaxf(redmax[2], redmax[3]));

    float sum = 0.f;
    float e[16];
#pragma unroll
    for (int k = 0; k < 16; ++k) {
        e[k] = __expf(vals[k] - m);  // exp(-inf)=0 handles the diagonal
        sum += e[k];
    }
#pragma unroll
    for (int off = 32; off >= 1; off >>= 1) sum += __shfl_xor(sum, off);
    if ((threadIdx.x & 63) == 0) redsum[threadIdx.x >> 6] = sum;
    __syncthreads();
    sum = redsum[0] + redsum[1] + redsum[2] + redsum[3];

    const float inv = 1.0f / sum;
#pragma unroll
    for (int k = 0; k < 16; ++k) {
        const int c = threadIdx.x + k * 256;
        __hip_bfloat16 h = __float2bfloat16(e[k] * inv);
        P[(long)row * N + c] = *(unsigned short*)&h;
    }
}

// ---------------------------------------------------------------------------
extern "C" void kernel_launch(void* const* d_in, const int* in_sizes, int n_in,
                              void* d_out, int out_size, void* d_ws, size_t ws_size,
                              hipStream_t stream) {
    const float* in = (const float*)d_in[0];
    float* out = (float*)d_out;

    // workspace layout: [xb: 32MB bf16] [Pb: 32MB bf16]; d_out doubles as
    // fp32 score scratch (gemm1 fully overwrites it, softmax reads it,
    // gemm2 fully overwrites it again).
    bf16* xb = (bf16*)d_ws;
    unsigned short* Pb = (unsigned short*)((char*)d_ws + (size_t)N * N * sizeof(bf16));
    float* S = out;

    cvt_scale<<<(N * (long)N) / (256 * 8), 256, 0, stream>>>(in, (unsigned short*)xb);

    dim3 grid(N / BN, N / BM);
    gemm_bt<<<grid, 256, 0, stream>>>(xb, xb, S);          // S = x x^T (scale folded)
    softmax_rows<<<N, 256, 0, stream>>>(S, Pb);            // P = softmax(mask(S))
    gemm_bt<<<grid, 256, 0, stream>>>((const bf16*)Pb, xb, out);  // out = P x^T
}

// Round 2
// 410.307 us; speedup vs baseline: 1.1504x; 1.1504x over previous
//
#include <hip/hip_runtime.h>
#include <hip/hip_bf16.h>
#include <stdint.h>

#define N 4096
#define BM 128
#define BN 128
#define BK 64

typedef __hip_bfloat16 bf16;
typedef __attribute__((ext_vector_type(8))) __bf16 bfrag;   // 8 bf16 = 4 VGPRs (MFMA A/B operand)
typedef __attribute__((ext_vector_type(4))) float floatx4;  // MFMA C/D operand

// ---------------------------------------------------------------------------
// async global -> LDS, 16B per lane (global_load_lds_dwordx4)
// LDS dest must be wave-uniform base + lane*16 -- our slot layout guarantees it.
// ---------------------------------------------------------------------------
__device__ __forceinline__ void gld_lds16(const void* g, void* l) {
    __builtin_amdgcn_global_load_lds(
        (const __attribute__((address_space(1))) void*)g,
        (__attribute__((address_space(3))) void*)l, 16, 0, 0);
}

// ---------------------------------------------------------------------------
// Kernel 1: out_bf16 = bf16(in_f32 * 1/64)   (fold the 1/sqrt(D) scale here)
// ---------------------------------------------------------------------------
__global__ __launch_bounds__(256) void cvt_scale(const float* __restrict__ in,
                                                 unsigned short* __restrict__ out) {
    const long i = ((long)blockIdx.x * 256 + threadIdx.x) * 8;
    float4 a = *(const float4*)(in + i);
    float4 b = *(const float4*)(in + i + 4);
    const float sc = 0.015625f;  // 1/64 = 1/sqrt(4096)
    float v[8] = {a.x, a.y, a.z, a.w, b.x, b.y, b.z, b.w};
    alignas(16) unsigned short r[8];
#pragma unroll
    for (int k = 0; k < 8; ++k) {
        __hip_bfloat16 h = __float2bfloat16(v[k] * sc);
        r[k] = *(unsigned short*)&h;
    }
    *(uint4*)(out + i) = *(const uint4*)r;
}

// ---------------------------------------------------------------------------
// Kernel 2/4: C[M,N] = A * B^T.  m97 structure + XOR-swizzled LDS k-blocks.
//
// LDS layout: slot (row, kb) [16B each, kb=0..7] holds global k-block
// (kb ^ (row&7)).  The swizzle is applied on the STAGING side by permuting
// which global 16B chunk each lane fetches (keeps global_load_lds's
// wave-uniform-base + lane*16 dest contract AND global coalescing, since
// lanes only permute within a 128B-aligned segment).  On the read side,
// fragment row r, k-block kw lives at slot kw ^ (r&7): the 16 lanes of each
// quad then spread over all 32 banks at 2 lanes/bank-group (2-way = free)
// instead of 16 lanes on one 4-bank group (16-way, the R1 5e7-conflict bug).
// ---------------------------------------------------------------------------
__global__ __launch_bounds__(256) void gemm_bt(const bf16* __restrict__ A,
                                               const bf16* __restrict__ B,
                                               float* __restrict__ C) {
    __shared__ bf16 As[BM * BK];  // 16 KB, [128 rows][8 slots of 16B]
    __shared__ bf16 Bs[BN * BK];  // 16 KB

    const int t    = threadIdx.x;
    const int lane = t & 63;
    const int wave = t >> 6;      // 0..3
    const int wm   = wave >> 1;   // wave row 0..1
    const int wn   = wave & 1;    // wave col 0..1
    const int bm   = blockIdx.y * BM;
    const int bn   = blockIdx.x * BN;

    floatx4 acc[4][4] = {};

    // staging: slot s = i*256 + t; row = s>>3, kb = s&7 (16B each).
    // lane fetches global k-block kb ^ (row&7)  [XOR swizzle].
    const int srow = t >> 3;                    // 0..31 (+32*i)
    const int skb  = (t & 7) ^ (srow & 7);      // swizzled source k-block
    const bf16* Ag = A + (long)(bm + srow) * N + skb * 8;
    const bf16* Bg = B + (long)(bn + srow) * N + skb * 8;
    bf16* Asl = As + t * 8;
    bf16* Bsl = Bs + t * 8;

    for (int k0 = 0; k0 < N; k0 += BK) {
#pragma unroll
        for (int i = 0; i < 4; ++i) {
            // (srow + 32*i) & 7 == srow & 7, so the same swizzled offset works
            gld_lds16(Ag + (long)i * 32 * N + k0, Asl + i * 2048);
            gld_lds16(Bg + (long)i * 32 * N + k0, Bsl + i * 2048);
        }
        __syncthreads();

        const int l15 = lane & 15;
        const int l7  = lane & 7;
        const int q   = lane >> 4;
#pragma unroll
        for (int kk = 0; kk < BK; kk += 32) {
            const int kw = (kk >> 3) + q;       // wanted k-block (16B units)
            const int sw = kw ^ l7;             // swizzled LDS slot
            bfrag a[4], b[4];
#pragma unroll
            for (int i = 0; i < 4; ++i)
                a[i] = *(const bfrag*)&As[((wm * 64 + i * 16 + l15) * 8 + sw) * 8];
#pragma unroll
            for (int j = 0; j < 4; ++j)
                b[j] = *(const bfrag*)&Bs[((wn * 64 + j * 16 + l15) * 8 + sw) * 8];
#pragma unroll
            for (int i = 0; i < 4; ++i)
#pragma unroll
                for (int j = 0; j < 4; ++j)
                    acc[i][j] = __builtin_amdgcn_mfma_f32_16x16x32_bf16(
                        a[i], b[j], acc[i][j], 0, 0, 0);
        }
        __syncthreads();
    }

    // epilogue: C/D layout col=lane&15, row=(lane>>4)*4+reg  [m89-verified]
    const int col0 = bn + wn * 64 + (lane & 15);
    const int row0 = bm + wm * 64 + (lane >> 4) * 4;
#pragma unroll
    for (int i = 0; i < 4; ++i)
#pragma unroll
        for (int j = 0; j < 4; ++j)
#pragma unroll
            for (int r = 0; r < 4; ++r)
                C[(long)(row0 + i * 16 + r) * N + col0 + j * 16] = acc[i][j][r];
}

// ---------------------------------------------------------------------------
// Kernel 3: row softmax with diagonal mask; fp32 in -> bf16 probabilities out.
// One 256-thread block per row; 16 elements/thread kept in registers.
// ---------------------------------------------------------------------------
__global__ __launch_bounds__(256) void softmax_rows(const float* __restrict__ S,
                                                    unsigned short* __restrict__ P) {
    const int row = blockIdx.x;
    const float* s = S + (long)row * N;
    __shared__ float redmax[4];
    __shared__ float redsum[4];

    float vals[16];
    float m = -INFINITY;
#pragma unroll
    for (int k = 0; k < 16; ++k) {
        const int c = threadIdx.x + k * 256;
        float v = s[c];
        if (c == row) v = -INFINITY;  // mask self-similarity
        vals[k] = v;
        m = fmaxf(m, v);
    }
#pragma unroll
    for (int off = 32; off >= 1; off >>= 1) m = fmaxf(m, __shfl_xor(m, off));
    if ((threadIdx.x & 63) == 0) redmax[threadIdx.x >> 6] = m;
    __syncthreads();
    m = fmaxf(fmaxf(redmax[0], redmax[1]), fmaxf(redmax[2], redmax[3]));

    float sum = 0.f;
    float e[16];
#pragma unroll
    for (int k = 0; k < 16; ++k) {
        e[k] = __expf(vals[k] - m);  // exp(-inf)=0 handles the diagonal
        sum += e[k];
    }
#pragma unroll
    for (int off = 32; off >= 1; off >>= 1) sum += __shfl_xor(sum, off);
    if ((threadIdx.x & 63) == 0) redsum[threadIdx.x >> 6] = sum;
    __syncthreads();
    sum = redsum[0] + redsum[1] + redsum[2] + redsum[3];

    const float inv = 1.0f / sum;
#pragma unroll
    for (int k = 0; k < 16; ++k) {
        const int c = threadIdx.x + k * 256;
        __hip_bfloat16 h = __float2bfloat16(e[k] * inv);
        P[(long)row * N + c] = *(unsigned short*)&h;
    }
}

// ---------------------------------------------------------------------------
extern "C" void kernel_launch(void* const* d_in, const int* in_sizes, int n_in,
                              void* d_out, int out_size, void* d_ws, size_t ws_size,
                              hipStream_t stream) {
    const float* in = (const float*)d_in[0];
    float* out = (float*)d_out;

    // workspace layout: [xb: 32MB bf16] [Pb: 32MB bf16]; d_out doubles as
    // fp32 score scratch (gemm1 fully overwrites it, softmax reads it,
    // gemm2 fully overwrites it again).
    bf16* xb = (bf16*)d_ws;
    unsigned short* Pb = (unsigned short*)((char*)d_ws + (size_t)N * N * sizeof(bf16));
    float* S = out;

    cvt_scale<<<(N * (long)N) / (256 * 8), 256, 0, stream>>>(in, (unsigned short*)xb);

    dim3 grid(N / BN, N / BM);
    gemm_bt<<<grid, 256, 0, stream>>>(xb, xb, S);          // S = x x^T (scale folded)
    softmax_rows<<<N, 256, 0, stream>>>(S, Pb);            // P = softmax(mask(S))
    gemm_bt<<<grid, 256, 0, stream>>>((const bf16*)Pb, xb, out);  // out = P x^T
}

// Round 3
// 394.326 us; speedup vs baseline: 1.1971x; 1.0405x over previous
//
#include <hip/hip_runtime.h>
#include <hip/hip_bf16.h>
#include <stdint.h>

#define N 4096
#define BM 128
#define BN 128
#define BK 64

typedef __hip_bfloat16 bf16;
typedef __attribute__((ext_vector_type(8))) __bf16 bfrag;   // 8 bf16 = 4 VGPRs (MFMA A/B operand)
typedef __attribute__((ext_vector_type(4))) float floatx4;  // MFMA C/D operand

// ---------------------------------------------------------------------------
// async global -> LDS, 16B per lane (global_load_lds_dwordx4)
// ---------------------------------------------------------------------------
__device__ __forceinline__ void gld_lds16(const void* g, void* l) {
    __builtin_amdgcn_global_load_lds(
        (const __attribute__((address_space(1))) void*)g,
        (__attribute__((address_space(3))) void*)l, 16, 0, 0);
}

// ---------------------------------------------------------------------------
// Kernel 1: out_bf16 = bf16(in_f32 * 1/64)   (fold the 1/sqrt(D) scale here)
// ---------------------------------------------------------------------------
__global__ __launch_bounds__(256) void cvt_scale(const float* __restrict__ in,
                                                 unsigned short* __restrict__ out) {
    const long i = ((long)blockIdx.x * 256 + threadIdx.x) * 8;
    float4 a = *(const float4*)(in + i);
    float4 b = *(const float4*)(in + i + 4);
    const float sc = 0.015625f;  // 1/64 = 1/sqrt(4096)
    float v[8] = {a.x, a.y, a.z, a.w, b.x, b.y, b.z, b.w};
    alignas(16) unsigned short r[8];
#pragma unroll
    for (int k = 0; k < 8; ++k) {
        __hip_bfloat16 h = __float2bfloat16(v[k] * sc);
        r[k] = *(unsigned short*)&h;
    }
    *(uint4*)(out + i) = *(const uint4*)r;
}

// ---------------------------------------------------------------------------
// Shared GEMM body: C = A * B^T on 128x128 tiles, BK=64, XOR-swizzled LDS
// (R2-verified: 0 bank conflicts, 875 TF).  MODE selects the fused epilogue:
//   MODE 0 (sims): e = exp(acc), diag masked to 0, write bf16 E, accumulate
//                  fp32 row sums via quad shfl-reduce + atomicAdd.
//   MODE 1 (out):  write fp32 acc * (1/rowsum[row])  -- softmax denominator
//                  commutes with the PV GEMM since it is row-uniform.
// ---------------------------------------------------------------------------
template <int MODE>
__global__ __launch_bounds__(256) void gemm_bt(const bf16* __restrict__ A,
                                               const bf16* __restrict__ B,
                                               void* __restrict__ Cv,
                                               float* __restrict__ rowsum) {
    __shared__ bf16 As[BM * BK];  // 16 KB, [128 rows][8 slots of 16B]
    __shared__ bf16 Bs[BN * BK];  // 16 KB

    const int t    = threadIdx.x;
    const int lane = t & 63;
    const int wave = t >> 6;      // 0..3
    const int wm   = wave >> 1;   // wave row 0..1
    const int wn   = wave & 1;    // wave col 0..1
    const int bm   = blockIdx.y * BM;
    const int bn   = blockIdx.x * BN;

    floatx4 acc[4][4] = {};

    // staging: slot s = i*256 + t; row = s>>3, kb = s&7 (16B each).
    // lane fetches global k-block kb ^ (row&7)  [XOR swizzle -> conflict-free
    // ds_read_b128 on the fragment side; global coalescing preserved since
    // lanes permute within one 128B segment].
    const int srow = t >> 3;                    // 0..31 (+32*i)
    const int skb  = (t & 7) ^ (srow & 7);      // swizzled source k-block
    const bf16* Ag = A + (long)(bm + srow) * N + skb * 8;
    const bf16* Bg = B + (long)(bn + srow) * N + skb * 8;
    bf16* Asl = As + t * 8;
    bf16* Bsl = Bs + t * 8;

    for (int k0 = 0; k0 < N; k0 += BK) {
#pragma unroll
        for (int i = 0; i < 4; ++i) {
            gld_lds16(Ag + (long)i * 32 * N + k0, Asl + i * 2048);
            gld_lds16(Bg + (long)i * 32 * N + k0, Bsl + i * 2048);
        }
        __syncthreads();

        const int l15 = lane & 15;
        const int l7  = lane & 7;
        const int q   = lane >> 4;
#pragma unroll
        for (int kk = 0; kk < BK; kk += 32) {
            const int kw = (kk >> 3) + q;       // wanted k-block (16B units)
            const int sw = kw ^ l7;             // swizzled LDS slot
            bfrag a[4], b[4];
#pragma unroll
            for (int i = 0; i < 4; ++i)
                a[i] = *(const bfrag*)&As[((wm * 64 + i * 16 + l15) * 8 + sw) * 8];
#pragma unroll
            for (int j = 0; j < 4; ++j)
                b[j] = *(const bfrag*)&Bs[((wn * 64 + j * 16 + l15) * 8 + sw) * 8];
#pragma unroll
            for (int i = 0; i < 4; ++i)
#pragma unroll
                for (int j = 0; j < 4; ++j)
                    acc[i][j] = __builtin_amdgcn_mfma_f32_16x16x32_bf16(
                        a[i], b[j], acc[i][j], 0, 0, 0);
        }
        __syncthreads();
    }

    // epilogue: C/D layout col=lane&15, row=(lane>>4)*4+reg  [m89-verified]
    const int col0 = bn + wn * 64 + (lane & 15);
    const int row0 = bm + wm * 64 + (lane >> 4) * 4;

    if (MODE == 0) {
        unsigned short* E = (unsigned short*)Cv;
#pragma unroll
        for (int i = 0; i < 4; ++i) {
#pragma unroll
            for (int r = 0; r < 4; ++r) {
                const int row = row0 + i * 16 + r;
                float rs = 0.f;
#pragma unroll
                for (int j = 0; j < 4; ++j) {
                    const int col = col0 + j * 16;
                    // no max-subtraction: sims ~ +-0.3, exp is safe; the
                    // reference's max-shift cancels in the normalization.
                    float e = (row == col) ? 0.f : __expf(acc[i][j][r]);
                    rs += e;
                    __hip_bfloat16 h = __float2bfloat16(e);
                    E[(long)row * N + col] = *(unsigned short*)&h;
                }
                // sum across the 16 lanes of the quad (same rows, cols 0..63
                // of this wave's 64-col strip), then one atomic per row/quad.
#pragma unroll
                for (int off = 1; off < 16; off <<= 1) rs += __shfl_xor(rs, off);
                if ((lane & 15) == 0) atomicAdd(rowsum + row, rs);
            }
        }
    } else {
        float* C = (float*)Cv;
#pragma unroll
        for (int i = 0; i < 4; ++i) {
#pragma unroll
            for (int r = 0; r < 4; ++r) {
                const int row = row0 + i * 16 + r;
                const float inv = 1.0f / rowsum[row];  // broadcast across quad
#pragma unroll
                for (int j = 0; j < 4; ++j)
                    C[(long)row * N + col0 + j * 16] = acc[i][j][r] * inv;
            }
        }
    }
}

// ---------------------------------------------------------------------------
extern "C" void kernel_launch(void* const* d_in, const int* in_sizes, int n_in,
                              void* d_out, int out_size, void* d_ws, size_t ws_size,
                              hipStream_t stream) {
    const float* in = (const float*)d_in[0];
    float* out = (float*)d_out;

    // workspace layout: [rowsum: 16KB fp32] [xb: 32MB bf16] [E: 32MB bf16]
    float* rowsum = (float*)d_ws;
    bf16* xb = (bf16*)((char*)d_ws + 16384);
    unsigned short* E = (unsigned short*)((char*)d_ws + 16384 + (size_t)N * N * sizeof(bf16));

    cvt_scale<<<(N * (long)N) / (256 * 8), 256, 0, stream>>>(in, (unsigned short*)xb);
    hipMemsetAsync(rowsum, 0, N * sizeof(float), stream);  // ws is poisoned 0xAA

    dim3 grid(N / BN, N / BM);
    // E = exp(mask(x x^T)), rowsum = row sums of E
    gemm_bt<0><<<grid, 256, 0, stream>>>(xb, xb, E, rowsum);
    // out = (E / rowsum) x^T
    gemm_bt<1><<<grid, 256, 0, stream>>>((const bf16*)E, xb, out, rowsum);
}

// Round 4
// 373.807 us; speedup vs baseline: 1.2628x; 1.0549x over previous
//
#include <hip/hip_runtime.h>
#include <hip/hip_bf16.h>
#include <stdint.h>

#define N 4096
#define BM 128
#define BN 128
#define BK 64

typedef __hip_bfloat16 bf16;
typedef __attribute__((ext_vector_type(8))) __bf16 bfrag;   // 8 bf16 = 4 VGPRs (MFMA A/B operand)
typedef __attribute__((ext_vector_type(4))) float floatx4;  // MFMA C/D operand

// ---------------------------------------------------------------------------
// async global -> LDS, 16B per lane (global_load_lds_dwordx4)
// ---------------------------------------------------------------------------
__device__ __forceinline__ void gld_lds16(const void* g, void* l) {
    __builtin_amdgcn_global_load_lds(
        (const __attribute__((address_space(1))) void*)g,
        (__attribute__((address_space(3))) void*)l, 16, 0, 0);
}

__device__ __forceinline__ unsigned short f2bf(float x) {
    __hip_bfloat16 h = __float2bfloat16(x);
    return *(unsigned short*)&h;
}

// ---------------------------------------------------------------------------
// Kernel 1: out_bf16 = bf16(in_f32 * 1/64)   (fold the 1/sqrt(D) scale here)
// ---------------------------------------------------------------------------
__global__ __launch_bounds__(256) void cvt_scale(const float* __restrict__ in,
                                                 unsigned short* __restrict__ out) {
    const long i = ((long)blockIdx.x * 256 + threadIdx.x) * 8;
    float4 a = *(const float4*)(in + i);
    float4 b = *(const float4*)(in + i + 4);
    const float sc = 0.015625f;  // 1/64 = 1/sqrt(4096)
    float v[8] = {a.x, a.y, a.z, a.w, b.x, b.y, b.z, b.w};
    alignas(16) unsigned short r[8];
#pragma unroll
    for (int k = 0; k < 8; ++k) r[k] = f2bf(v[k] * sc);
    *(uint4*)(out + i) = *(const uint4*)r;
}

// ---------------------------------------------------------------------------
// Kernel 2 (gemm_sym): E = exp(mask(x x^T)) exploiting SYMMETRY.
// Triangular 1D grid of 528 blocks (32 diag + 496 lower).  Each off-diag
// block computes one 128x128 tile and writes BOTH it and its transpose
// (per-wave 64x64 transpose through XOR-swizzled LDS reusing the dead
// As/Bs staging space), and accumulates rowsum for rows (row-sums) and for
// mirror rows (column-sums).  E is bit-identical to the full-grid version.
// K-loop identical to the R2-verified 875 TF / 0-conflict structure.
// ---------------------------------------------------------------------------
__global__ __launch_bounds__(256) void gemm_sym(const bf16* __restrict__ X,
                                                unsigned short* __restrict__ E,
                                                float* __restrict__ rowsum) {
    __shared__ __align__(16) char smem[32768];
    bf16* As = (bf16*)smem;            // [BM*BK] = 16 KB
    bf16* Bs = (bf16*)(smem + 16384);  // 16 KB

    const int t    = threadIdx.x;
    const int lane = t & 63;
    const int wave = t >> 6;
    const int wm   = wave >> 1;
    const int wn   = wave & 1;

    // decode triangular block index: b = I*(I+1)/2 + J, J <= I
    const int b = blockIdx.x;
    int I = (int)((sqrtf((float)(8 * b + 1)) - 1.0f) * 0.5f);
    if ((I + 1) * (I + 2) / 2 <= b) ++I;   // fp-safety fixups
    if (I * (I + 1) / 2 > b) --I;
    const int Jb = b - I * (I + 1) / 2;
    const int bm = I * BM;   // row block (>= col block)
    const int bn = Jb * BM;
    const bool diag = (I == Jb);

    floatx4 acc[4][4] = {};

    // staging with XOR-swizzled k-blocks (R2: 0 bank conflicts)
    const int srow = t >> 3;
    const int skb  = (t & 7) ^ (srow & 7);
    const bf16* Ag = X + (long)(bm + srow) * N + skb * 8;
    const bf16* Bg = X + (long)(bn + srow) * N + skb * 8;
    bf16* Asl = As + t * 8;
    bf16* Bsl = Bs + t * 8;

    for (int k0 = 0; k0 < N; k0 += BK) {
#pragma unroll
        for (int i = 0; i < 4; ++i) {
            gld_lds16(Ag + (long)i * 32 * N + k0, Asl + i * 2048);
            gld_lds16(Bg + (long)i * 32 * N + k0, Bsl + i * 2048);
        }
        __syncthreads();

        const int l15i = lane & 15;
        const int l7   = lane & 7;
        const int qi   = lane >> 4;
#pragma unroll
        for (int kk = 0; kk < BK; kk += 32) {
            const int kw = (kk >> 3) + qi;
            const int sw = kw ^ l7;
            bfrag a[4], bb[4];
#pragma unroll
            for (int i = 0; i < 4; ++i)
                a[i] = *(const bfrag*)&As[((wm * 64 + i * 16 + l15i) * 8 + sw) * 8];
#pragma unroll
            for (int j = 0; j < 4; ++j)
                bb[j] = *(const bfrag*)&Bs[((wn * 64 + j * 16 + l15i) * 8 + sw) * 8];
#pragma unroll
            for (int i = 0; i < 4; ++i)
#pragma unroll
                for (int j = 0; j < 4; ++j)
                    acc[i][j] = __builtin_amdgcn_mfma_f32_16x16x32_bf16(
                        a[i], bb[j], acc[i][j], 0, 0, 0);
        }
        __syncthreads();
    }

    // ---- epilogue: C/D layout col=lane&15, row=(lane>>4)*4+reg ----
    const int l15  = lane & 15;
    const int q    = lane >> 4;
    const int col0 = bn + wn * 64 + l15;
    const int row0 = bm + wm * 64 + q * 4;

    // exp (in place), normal-tile write, row sums
#pragma unroll
    for (int i = 0; i < 4; ++i) {
#pragma unroll
        for (int r = 0; r < 4; ++r) {
            const int row = row0 + i * 16 + r;
            float rs = 0.f;
#pragma unroll
            for (int j = 0; j < 4; ++j) {
                const int col = col0 + j * 16;
                // no max-subtraction: sims ~ +-0.3, exp safe; shift cancels.
                float e = (row == col) ? 0.f : __expf(acc[i][j][r]);
                acc[i][j][r] = e;
                rs += e;
                E[(long)row * N + col] = f2bf(e);
            }
#pragma unroll
            for (int off = 1; off < 16; off <<= 1) rs += __shfl_xor(rs, off);
            if (l15 == 0) atomicAdd(rowsum + row, rs);
        }
    }

    if (!diag) {
        // column sums -> row sums of the mirror tile
#pragma unroll
        for (int j = 0; j < 4; ++j) {
            float cs = 0.f;
#pragma unroll
            for (int i = 0; i < 4; ++i)
#pragma unroll
                for (int r = 0; r < 4; ++r) cs += acc[i][j][r];
            cs += __shfl_xor(cs, 16);
            cs += __shfl_xor(cs, 32);
            if (q == 0) atomicAdd(rowsum + bn + wn * 64 + j * 16 + l15, cs);
        }

        // per-wave 64x64 transpose through swizzled LDS (aliases As/Bs).
        // store: value (lr, lc) of this wave's quadrant at
        //   tb[lc*64 + 8*((lr>>3) ^ (lc&7)) + 4*((lr>>2)&1) + (lr&3)]
        // -> readout of transposed row tr is a conflict-free ds_read_b128.
        unsigned short* tb = (unsigned short*)smem + wave * 4096;  // 8 KB/wave
        __syncthreads();  // staging buffers are dead; all waves past K-loop
#pragma unroll
        for (int i = 0; i < 4; ++i) {
            const int lr0 = i * 16 + q * 4;        // 4 consecutive rows (regs)
            const int blk = lr0 >> 3;              // 16B-block index of lr0
            const int half = (lr0 >> 2) & 1;       // 8B half within block
#pragma unroll
            for (int j = 0; j < 4; ++j) {
                const int lc = j * 16 + l15;
                union { unsigned short u[4]; uint2 v2; } pk;
#pragma unroll
                for (int r = 0; r < 4; ++r) pk.u[r] = f2bf(acc[i][j][r]);
                *(uint2*)&tb[lc * 64 + 8 * (blk ^ (lc & 7)) + 4 * half] = pk.v2;
            }
        }
        __syncthreads();  // wave-internal RAW insurance (cheap, uniform)

        // coalesced write of the mirror tile: global row bn+wn*64+gr,
        // cols bm+wm*64 .. +63, 16B per lane.
        const int gr0 = lane >> 3;
        const int cb  = lane & 7;
#pragma unroll
        for (int p = 0; p < 8; ++p) {
            const int gr = p * 8 + gr0;
            uint4 v = *(const uint4*)&tb[gr * 64 + 8 * (cb ^ (gr & 7))];
            *(uint4*)&E[(long)(bn + wn * 64 + gr) * N + bm + wm * 64 + cb * 8] = v;
        }
    }
}

// ---------------------------------------------------------------------------
// Kernel 3 (gemm_pv): out = (E/rowsum) x^T -- unchanged R2-verified GEMM with
// the row-uniform 1/rowsum fused into the epilogue.
// ---------------------------------------------------------------------------
__global__ __launch_bounds__(256) void gemm_pv(const bf16* __restrict__ A,
                                               const bf16* __restrict__ B,
                                               float* __restrict__ C,
                                               const float* __restrict__ rowsum) {
    __shared__ bf16 As[BM * BK];
    __shared__ bf16 Bs[BN * BK];

    const int t    = threadIdx.x;
    const int lane = t & 63;
    const int wave = t >> 6;
    const int wm   = wave >> 1;
    const int wn   = wave & 1;
    const int bm   = blockIdx.y * BM;
    const int bn   = blockIdx.x * BN;

    floatx4 acc[4][4] = {};

    const int srow = t >> 3;
    const int skb  = (t & 7) ^ (srow & 7);
    const bf16* Ag = A + (long)(bm + srow) * N + skb * 8;
    const bf16* Bg = B + (long)(bn + srow) * N + skb * 8;
    bf16* Asl = As + t * 8;
    bf16* Bsl = Bs + t * 8;

    for (int k0 = 0; k0 < N; k0 += BK) {
#pragma unroll
        for (int i = 0; i < 4; ++i) {
            gld_lds16(Ag + (long)i * 32 * N + k0, Asl + i * 2048);
            gld_lds16(Bg + (long)i * 32 * N + k0, Bsl + i * 2048);
        }
        __syncthreads();

        const int l15 = lane & 15;
        const int l7  = lane & 7;
        const int q   = lane >> 4;
#pragma unroll
        for (int kk = 0; kk < BK; kk += 32) {
            const int kw = (kk >> 3) + q;
            const int sw = kw ^ l7;
            bfrag a[4], b[4];
#pragma unroll
            for (int i = 0; i < 4; ++i)
                a[i] = *(const bfrag*)&As[((wm * 64 + i * 16 + l15) * 8 + sw) * 8];
#pragma unroll
            for (int j = 0; j < 4; ++j)
                b[j] = *(const bfrag*)&Bs[((wn * 64 + j * 16 + l15) * 8 + sw) * 8];
#pragma unroll
            for (int i = 0; i < 4; ++i)
#pragma unroll
                for (int j = 0; j < 4; ++j)
                    acc[i][j] = __builtin_amdgcn_mfma_f32_16x16x32_bf16(
                        a[i], b[j], acc[i][j], 0, 0, 0);
        }
        __syncthreads();
    }

    const int col0 = bn + wn * 64 + (lane & 15);
    const int row0 = bm + wm * 64 + (lane >> 4) * 4;
#pragma unroll
    for (int i = 0; i < 4; ++i) {
#pragma unroll
        for (int r = 0; r < 4; ++r) {
            const int row = row0 + i * 16 + r;
            const float inv = 1.0f / rowsum[row];
#pragma unroll
            for (int j = 0; j < 4; ++j)
                C[(long)row * N + col0 + j * 16] = acc[i][j][r] * inv;
        }
    }
}

// ---------------------------------------------------------------------------
extern "C" void kernel_launch(void* const* d_in, const int* in_sizes, int n_in,
                              void* d_out, int out_size, void* d_ws, size_t ws_size,
                              hipStream_t stream) {
    const float* in = (const float*)d_in[0];
    float* out = (float*)d_out;

    // workspace layout: [rowsum: 16KB fp32] [xb: 32MB bf16] [E: 32MB bf16]
    float* rowsum = (float*)d_ws;
    bf16* xb = (bf16*)((char*)d_ws + 16384);
    unsigned short* E = (unsigned short*)((char*)d_ws + 16384 + (size_t)N * N * sizeof(bf16));

    cvt_scale<<<(N * (long)N) / (256 * 8), 256, 0, stream>>>(in, (unsigned short*)xb);
    hipMemsetAsync(rowsum, 0, N * sizeof(float), stream);  // ws is poisoned 0xAA

    // E = exp(mask(x x^T)) via 528 triangular tiles, rowsum = row sums of E
    gemm_sym<<<528, 256, 0, stream>>>(xb, E, rowsum);
    // out = (E / rowsum) x^T
    dim3 grid(N / BN, N / BM);
    gemm_pv<<<grid, 256, 0, stream>>>((const bf16*)E, xb, out, rowsum);
}

// Round 5
// 372.396 us; speedup vs baseline: 1.2675x; 1.0038x over previous
//
#include <hip/hip_runtime.h>
#include <hip/hip_bf16.h>
#include <stdint.h>

#define N 4096
#define BM 128
#define BN 128
#define BK 64

typedef __hip_bfloat16 bf16;
typedef __attribute__((ext_vector_type(8))) __bf16 bfrag;   // 8 bf16 = 4 VGPRs (MFMA A/B operand)
typedef __attribute__((ext_vector_type(4))) float floatx4;  // MFMA C/D operand

// ---------------------------------------------------------------------------
// async global -> LDS, 16B per lane (global_load_lds_dwordx4)
// ---------------------------------------------------------------------------
__device__ __forceinline__ void gld_lds16(const void* g, void* l) {
    __builtin_amdgcn_global_load_lds(
        (const __attribute__((address_space(1))) void*)g,
        (__attribute__((address_space(3))) void*)l, 16, 0, 0);
}

__device__ __forceinline__ unsigned short f2bf(float x) {
    __hip_bfloat16 h = __float2bfloat16(x);
    return *(unsigned short*)&h;
}

// ---------------------------------------------------------------------------
// Kernel 1: out_bf16 = bf16(in_f32 * 1/64); blocks 0..15 also zero rowsum
// (replaces the separate hipMemsetAsync dispatch -- stream order guarantees
// completion before gemm_sym).
// ---------------------------------------------------------------------------
__global__ __launch_bounds__(256) void cvt_scale(const float* __restrict__ in,
                                                 unsigned short* __restrict__ out,
                                                 float* __restrict__ rowsum) {
    if (blockIdx.x < 16) rowsum[blockIdx.x * 256 + threadIdx.x] = 0.f;
    const long i = ((long)blockIdx.x * 256 + threadIdx.x) * 8;
    float4 a = *(const float4*)(in + i);
    float4 b = *(const float4*)(in + i + 4);
    const float sc = 0.015625f;  // 1/64 = 1/sqrt(4096)
    float v[8] = {a.x, a.y, a.z, a.w, b.x, b.y, b.z, b.w};
    alignas(16) unsigned short r[8];
#pragma unroll
    for (int k = 0; k < 8; ++k) r[k] = f2bf(v[k] * sc);
    *(uint4*)(out + i) = *(const uint4*)r;
}

// ---------------------------------------------------------------------------
// Kernel 2 (gemm_sym): E = exp(mask(x x^T)) exploiting SYMMETRY.
// Triangular grid of 528 blocks -- but with 512 THREADS (8 waves) per block:
// R4 post-mortem showed 528 x 4-wave blocks = 8.2 waves/CU, latency-bound
// (runtime ~invariant vs the full GEMM).  8 waves restores ~16.5 waves/CU,
// matching gemm_pv's occupancy.  Wave grid 2x4: wave tile 64 rows x 32 cols,
// acc[4][2].  K-loop math per output element is bit-identical to R4.
// ---------------------------------------------------------------------------
__global__ __launch_bounds__(512) void gemm_sym(const bf16* __restrict__ X,
                                                unsigned short* __restrict__ E,
                                                float* __restrict__ rowsum) {
    __shared__ __align__(16) char smem[32768];
    bf16* As = (bf16*)smem;            // [BM*BK] = 16 KB
    bf16* Bs = (bf16*)(smem + 16384);  // 16 KB

    const int t    = threadIdx.x;
    const int lane = t & 63;
    const int wave = t >> 6;      // 0..7
    const int wm   = wave >> 2;   // 0..1  (64-row strip)
    const int wn   = wave & 3;    // 0..3  (32-col strip)

    // decode triangular block index: b = I*(I+1)/2 + J, J <= I
    const int b = blockIdx.x;
    int I = (int)((sqrtf((float)(8 * b + 1)) - 1.0f) * 0.5f);
    if ((I + 1) * (I + 2) / 2 <= b) ++I;   // fp-safety fixups
    if (I * (I + 1) / 2 > b) --I;
    const int Jb = b - I * (I + 1) / 2;
    const int bm = I * BM;   // row block (>= col block)
    const int bn = Jb * BM;
    const bool diag = (I == Jb);

    floatx4 acc[4][2] = {};

    // staging with XOR-swizzled k-blocks (R2: 0 bank conflicts).
    // 512 threads: slot s = i*512 + t; row = s>>3 (64 rows per issue), kb = s&7.
    const int srow = t >> 3;                    // 0..63 (+64*i)
    const int skb  = (t & 7) ^ (srow & 7);      // swizzled source k-block
    const bf16* Ag = X + (long)(bm + srow) * N + skb * 8;
    const bf16* Bg = X + (long)(bn + srow) * N + skb * 8;
    bf16* Asl = As + t * 8;
    bf16* Bsl = Bs + t * 8;

    for (int k0 = 0; k0 < N; k0 += BK) {
#pragma unroll
        for (int i = 0; i < 2; ++i) {
            // (srow + 64*i) & 7 == srow & 7, so the same swizzle offset works
            gld_lds16(Ag + (long)i * 64 * N + k0, Asl + i * 4096);
            gld_lds16(Bg + (long)i * 64 * N + k0, Bsl + i * 4096);
        }
        __syncthreads();

        const int l15i = lane & 15;
        const int l7   = lane & 7;
        const int qi   = lane >> 4;
#pragma unroll
        for (int kk = 0; kk < BK; kk += 32) {
            const int kw = (kk >> 3) + qi;
            const int sw = kw ^ l7;
            bfrag a[4], bb[2];
#pragma unroll
            for (int i = 0; i < 4; ++i)
                a[i] = *(const bfrag*)&As[((wm * 64 + i * 16 + l15i) * 8 + sw) * 8];
#pragma unroll
            for (int j = 0; j < 2; ++j)
                bb[j] = *(const bfrag*)&Bs[((wn * 32 + j * 16 + l15i) * 8 + sw) * 8];
#pragma unroll
            for (int i = 0; i < 4; ++i)
#pragma unroll
                for (int j = 0; j < 2; ++j)
                    acc[i][j] = __builtin_amdgcn_mfma_f32_16x16x32_bf16(
                        a[i], bb[j], acc[i][j], 0, 0, 0);
        }
        __syncthreads();
    }

    // ---- epilogue: C/D layout col=lane&15, row=(lane>>4)*4+reg ----
    const int l15  = lane & 15;
    const int q    = lane >> 4;
    const int col0 = bn + wn * 32 + l15;
    const int row0 = bm + wm * 64 + q * 4;

    // exp (in place), normal-tile write, row sums (each wave covers 32 cols)
#pragma unroll
    for (int i = 0; i < 4; ++i) {
#pragma unroll
        for (int r = 0; r < 4; ++r) {
            const int row = row0 + i * 16 + r;
            float rs = 0.f;
#pragma unroll
            for (int j = 0; j < 2; ++j) {
                const int col = col0 + j * 16;
                // no max-subtraction: sims ~ +-0.3, exp safe; shift cancels.
                float e = (row == col) ? 0.f : __expf(acc[i][j][r]);
                acc[i][j][r] = e;
                rs += e;
                E[(long)row * N + col] = f2bf(e);
            }
#pragma unroll
            for (int off = 1; off < 16; off <<= 1) rs += __shfl_xor(rs, off);
            if (l15 == 0) atomicAdd(rowsum + row, rs);
        }
    }

    if (!diag) {
        // column sums -> row sums of the mirror tile (wave covers 32 cols)
#pragma unroll
        for (int j = 0; j < 2; ++j) {
            float cs = 0.f;
#pragma unroll
            for (int i = 0; i < 4; ++i)
#pragma unroll
                for (int r = 0; r < 4; ++r) cs += acc[i][j][r];
            cs += __shfl_xor(cs, 16);
            cs += __shfl_xor(cs, 32);
            if (q == 0) atomicAdd(rowsum + bn + wn * 32 + j * 16 + l15, cs);
        }

        // per-wave 32x64 transpose through swizzled LDS (aliases As/Bs).
        // store value (lr, lc) at tb[lc*64 + 8*((lr>>3)^(lc&7)) + 4*((lr>>2)&1)
        // + (lr&3)] -> readout of transposed row is a conflict-free b128.
        unsigned short* tb = (unsigned short*)smem + wave * 2048;  // 4 KB/wave
        __syncthreads();  // staging buffers dead; all waves past K-loop
#pragma unroll
        for (int i = 0; i < 4; ++i) {
            const int lr0 = i * 16 + q * 4;        // 4 consecutive rows (regs)
            const int blk = lr0 >> 3;
            const int half = (lr0 >> 2) & 1;
#pragma unroll
            for (int j = 0; j < 2; ++j) {
                const int lc = j * 16 + l15;       // 0..31 local col
                union { unsigned short u[4]; uint2 v2; } pk;
#pragma unroll
                for (int r = 0; r < 4; ++r) pk.u[r] = f2bf(acc[i][j][r]);
                *(uint2*)&tb[lc * 64 + 8 * (blk ^ (lc & 7)) + 4 * half] = pk.v2;
            }
        }
        __syncthreads();

        // coalesced mirror write: rows bn+wn*32+gr (gr 0..31), cols bm+wm*64..+63
        const int gr0 = lane >> 3;
        const int cb  = lane & 7;
#pragma unroll
        for (int p = 0; p < 4; ++p) {
            const int gr = p * 8 + gr0;
            uint4 v = *(const uint4*)&tb[gr * 64 + 8 * (cb ^ (gr & 7))];
            *(uint4*)&E[(long)(bn + wn * 32 + gr) * N + bm + wm * 64 + cb * 8] = v;
        }
    }
}

// ---------------------------------------------------------------------------
// Kernel 3 (gemm_pv): out = (E/rowsum) x^T -- unchanged R2-verified GEMM with
// the row-uniform 1/rowsum fused into the epilogue.  (875 TF plateau, 0
// conflicts; 1024 blocks = 16 waves/CU.)
// ---------------------------------------------------------------------------
__global__ __launch_bounds__(256) void gemm_pv(const bf16* __restrict__ A,
                                               const bf16* __restrict__ B,
                                               float* __restrict__ C,
                                               const float* __restrict__ rowsum) {
    __shared__ bf16 As[BM * BK];
    __shared__ bf16 Bs[BN * BK];

    const int t    = threadIdx.x;
    const int lane = t & 63;
    const int wave = t >> 6;
    const int wm   = wave >> 1;
    const int wn   = wave & 1;
    const int bm   = blockIdx.y * BM;
    const int bn   = blockIdx.x * BN;

    floatx4 acc[4][4] = {};

    const int srow = t >> 3;
    const int skb  = (t & 7) ^ (srow & 7);
    const bf16* Ag = A + (long)(bm + srow) * N + skb * 8;
    const bf16* Bg = B + (long)(bn + srow) * N + skb * 8;
    bf16* Asl = As + t * 8;
    bf16* Bsl = Bs + t * 8;

    for (int k0 = 0; k0 < N; k0 += BK) {
#pragma unroll
        for (int i = 0; i < 4; ++i) {
            gld_lds16(Ag + (long)i * 32 * N + k0, Asl + i * 2048);
            gld_lds16(Bg + (long)i * 32 * N + k0, Bsl + i * 2048);
        }
        __syncthreads();

        const int l15 = lane & 15;
        const int l7  = lane & 7;
        const int q   = lane >> 4;
#pragma unroll
        for (int kk = 0; kk < BK; kk += 32) {
            const int kw = (kk >> 3) + q;
            const int sw = kw ^ l7;
            bfrag a[4], b[4];
#pragma unroll
            for (int i = 0; i < 4; ++i)
                a[i] = *(const bfrag*)&As[((wm * 64 + i * 16 + l15) * 8 + sw) * 8];
#pragma unroll
            for (int j = 0; j < 4; ++j)
                b[j] = *(const bfrag*)&Bs[((wn * 64 + j * 16 + l15) * 8 + sw) * 8];
#pragma unroll
            for (int i = 0; i < 4; ++i)
#pragma unroll
                for (int j = 0; j < 4; ++j)
                    acc[i][j] = __builtin_amdgcn_mfma_f32_16x16x32_bf16(
                        a[i], b[j], acc[i][j], 0, 0, 0);
        }
        __syncthreads();
    }

    const int col0 = bn + wn * 64 + (lane & 15);
    const int row0 = bm + wm * 64 + (lane >> 4) * 4;
#pragma unroll
    for (int i = 0; i < 4; ++i) {
#pragma unroll
        for (int r = 0; r < 4; ++r) {
            const int row = row0 + i * 16 + r;
            const float inv = 1.0f / rowsum[row];
#pragma unroll
            for (int j = 0; j < 4; ++j)
                C[(long)row * N + col0 + j * 16] = acc[i][j][r] * inv;
        }
    }
}

// ---------------------------------------------------------------------------
extern "C" void kernel_launch(void* const* d_in, const int* in_sizes, int n_in,
                              void* d_out, int out_size, void* d_ws, size_t ws_size,
                              hipStream_t stream) {
    const float* in = (const float*)d_in[0];
    float* out = (float*)d_out;

    // workspace layout: [rowsum: 16KB fp32] [xb: 32MB bf16] [E: 32MB bf16]
    float* rowsum = (float*)d_ws;
    bf16* xb = (bf16*)((char*)d_ws + 16384);
    unsigned short* E = (unsigned short*)((char*)d_ws + 16384 + (size_t)N * N * sizeof(bf16));

    // convert + fold 1/sqrt(D); also zeroes rowsum (ws is poisoned 0xAA)
    cvt_scale<<<(N * (long)N) / (256 * 8), 256, 0, stream>>>(in, (unsigned short*)xb, rowsum);

    // E = exp(mask(x x^T)) via 528 triangular tiles (8 waves/block), rowsum
    gemm_sym<<<528, 512, 0, stream>>>(xb, E, rowsum);
    // out = (E / rowsum) x^T
    dim3 grid(N / BN, N / BM);
    gemm_pv<<<grid, 256, 0, stream>>>((const bf16*)E, xb, out, rowsum);
}

// Round 6
// 323.588 us; speedup vs baseline: 1.4587x; 1.1508x over previous
//
#include <hip/hip_runtime.h>
#include <hip/hip_bf16.h>
#include <stdint.h>

#define N 4096
#define BM 128
#define BN 128
#define BK 64      // bf16 K-tile (gemm_pv)
#define BK8 128    // fp8 K-tile (gemm_sym)

typedef __hip_bfloat16 bf16;
typedef __attribute__((ext_vector_type(8))) __bf16 bfrag;   // 8 bf16 (MFMA A/B operand)
typedef __attribute__((ext_vector_type(4))) float floatx4;  // MFMA C/D operand
typedef __attribute__((ext_vector_type(8))) int i32x8;      // 32 fp8 (f8f6f4 A/B operand)
typedef __attribute__((ext_vector_type(4))) int i32x4;

// ---------------------------------------------------------------------------
// async global -> LDS, 16B per lane (global_load_lds_dwordx4)
// ---------------------------------------------------------------------------
__device__ __forceinline__ void gld_lds16(const void* g, void* l) {
    __builtin_amdgcn_global_load_lds(
        (const __attribute__((address_space(1))) void*)g,
        (__attribute__((address_space(3))) void*)l, 16, 0, 0);
}

__device__ __forceinline__ unsigned short f2bf(float x) {
    __hip_bfloat16 h = __float2bfloat16(x);
    return *(unsigned short*)&h;
}

// ---------------------------------------------------------------------------
// Kernel 1: xb = bf16(in * 1/64)  (scaled, for gemm_pv's B operand)
//           x8 = fp8_e4m3(in)     (UNSCALED -- full e4m3 relative precision;
//                                  the 1/4096 is applied exactly via the MFMA
//                                  e8m0 scale operands, 2^-6 per operand)
// blocks 0..15 also zero rowsum (replaces the memset dispatch).
// ---------------------------------------------------------------------------
__global__ __launch_bounds__(256) void cvt_scale(const float* __restrict__ in,
                                                 unsigned short* __restrict__ xb,
                                                 uint8_t* __restrict__ x8,
                                                 float* __restrict__ rowsum) {
    if (blockIdx.x < 16) rowsum[blockIdx.x * 256 + threadIdx.x] = 0.f;
    const long i = ((long)blockIdx.x * 256 + threadIdx.x) * 8;
    float4 a = *(const float4*)(in + i);
    float4 b = *(const float4*)(in + i + 4);
    const float sc = 0.015625f;  // 1/64 = 1/sqrt(4096)
    float v[8] = {a.x, a.y, a.z, a.w, b.x, b.y, b.z, b.w};
    alignas(16) unsigned short r[8];
#pragma unroll
    for (int k = 0; k < 8; ++k) r[k] = f2bf(v[k] * sc);
    *(uint4*)(xb + i) = *(const uint4*)r;

    int p0 = __builtin_amdgcn_cvt_pk_fp8_f32(v[0], v[1], 0, false);
    p0     = __builtin_amdgcn_cvt_pk_fp8_f32(v[2], v[3], p0, true);
    int p1 = __builtin_amdgcn_cvt_pk_fp8_f32(v[4], v[5], 0, false);
    p1     = __builtin_amdgcn_cvt_pk_fp8_f32(v[6], v[7], p1, true);
    int2 pk; pk.x = p0; pk.y = p1;
    *(int2*)(x8 + i) = pk;
}

// ---------------------------------------------------------------------------
// Kernel 2 (gemm_sym): E = exp(mask(x x^T)), triangular 528-block grid,
// 512 threads (8 waves, 2x4 wave grid, 64x32 wave tile).
// R5 post-mortem: sym is K-loop ITERATION-bound (64 barrier-drained iters x
// 1.5x static imbalance), invariant to work/occupancy.  Fix: fp8 e4m3 at
// BK=128 -- same 32 KB LDS and 32 KB staging per iter, but HALF the
// iterations (32), and 4x fewer MFMAs at 2x rate via
// mfma_scale_f32_16x16x128_f8f6f4 (identity-ish e8m0 scales = 2^-6 each,
// applying the exact 1/4096 score scale in hardware).
// LDS swizzle: slot (row, b) holds global 16B k-block b^(row&7); fragment
// read slot = (2q+se)^l7 -- within each 16-lane phase q is constant, so
// banks see 2-way aliasing only (free, m136).  Same verified structure.
// ---------------------------------------------------------------------------
__global__ __launch_bounds__(512) void gemm_sym(const uint8_t* __restrict__ X8,
                                                unsigned short* __restrict__ E,
                                                float* __restrict__ rowsum) {
    __shared__ __align__(16) char smem[32768];
    uint8_t* As = (uint8_t*)smem;            // [128 rows][128 B] = 16 KB
    uint8_t* Bs = (uint8_t*)(smem + 16384);  // 16 KB

    const int t    = threadIdx.x;
    const int lane = t & 63;
    const int wave = t >> 6;      // 0..7
    const int wm   = wave >> 2;   // 0..1  (64-row strip)
    const int wn   = wave & 3;    // 0..3  (32-col strip)

    // decode triangular block index: b = I*(I+1)/2 + J, J <= I
    const int b = blockIdx.x;
    int I = (int)((sqrtf((float)(8 * b + 1)) - 1.0f) * 0.5f);
    if ((I + 1) * (I + 2) / 2 <= b) ++I;   // fp-safety fixups
    if (I * (I + 1) / 2 > b) --I;
    const int Jb = b - I * (I + 1) / 2;
    const int bm = I * BM;   // row block (>= col block)
    const int bn = Jb * BM;
    const bool diag = (I == Jb);

    floatx4 acc[4][2] = {};

    // staging: slot s = i*512 + t; row = s>>3 (64 rows/issue), 16B-block = s&7,
    // holding global k-block (s&7)^(row&7)  [XOR swizzle, source-side]
    const int srow = t >> 3;                    // 0..63 (+64*i)
    const int skb  = (t & 7) ^ (srow & 7);
    const uint8_t* Ag = X8 + (long)(bm + srow) * N + skb * 16;
    const uint8_t* Bg = X8 + (long)(bn + srow) * N + skb * 16;
    uint8_t* Asl = As + t * 16;
    uint8_t* Bsl = Bs + t * 16;

    for (int k0 = 0; k0 < N; k0 += BK8) {
#pragma unroll
        for (int i = 0; i < 2; ++i) {
            // (srow + 64*i) & 7 == srow & 7: same swizzled offset works
            gld_lds16(Ag + (long)i * 64 * N + k0, Asl + i * 8192);
            gld_lds16(Bg + (long)i * 64 * N + k0, Bsl + i * 8192);
        }
        __syncthreads();

        const int l15 = lane & 15;
        const int l7  = lane & 7;
        const int q   = lane >> 4;
        // A-frag (16x128 tile): lane holds row=l15, k = q*32 .. q*32+31
        // = 16B-blocks 2q, 2q+1 (swizzled slots (2q+se)^l7; row&7==l7 since
        // wm*64, i*16, wn*32 are all multiples of 8/16).
        i32x8 af[4], bfr[2];
#pragma unroll
        for (int i = 0; i < 4; ++i) {
            const int row = wm * 64 + i * 16 + l15;
            i32x4 lo = *(const i32x4*)&As[(row * 8 + ((2 * q) ^ l7)) * 16];
            i32x4 hi = *(const i32x4*)&As[(row * 8 + ((2 * q + 1) ^ l7)) * 16];
            af[i] = (i32x8){lo.x, lo.y, lo.z, lo.w, hi.x, hi.y, hi.z, hi.w};
        }
#pragma unroll
        for (int j = 0; j < 2; ++j) {
            const int row = wn * 32 + j * 16 + l15;
            i32x4 lo = *(const i32x4*)&Bs[(row * 8 + ((2 * q) ^ l7)) * 16];
            i32x4 hi = *(const i32x4*)&Bs[(row * 8 + ((2 * q + 1) ^ l7)) * 16];
            bfr[j] = (i32x8){lo.x, lo.y, lo.z, lo.w, hi.x, hi.y, hi.z, hi.w};
        }
#pragma unroll
        for (int i = 0; i < 4; ++i)
#pragma unroll
            for (int j = 0; j < 2; ++j)
                acc[i][j] = __builtin_amdgcn_mfma_scale_f32_16x16x128_f8f6f4(
                    af[i], bfr[j], acc[i][j],
                    0, 0,               // cbsz=0 (A fp8 e4m3), blgp=0 (B fp8)
                    0, 0x79797979,      // A scale: e8m0 121 = 2^-6, all bytes
                    0, 0x79797979);     // B scale: 2^-6  (product: 1/4096)
        __syncthreads();
    }

    // ---- epilogue: C/D layout col=lane&15, row=(lane>>4)*4+reg ----
    // (f8f6f4 C/D layout is shape-determined, same as bf16 16x16 -- m121-128)
    const int l15  = lane & 15;
    const int q    = lane >> 4;
    const int col0 = bn + wn * 32 + l15;
    const int row0 = bm + wm * 64 + q * 4;

#pragma unroll
    for (int i = 0; i < 4; ++i) {
#pragma unroll
        for (int r = 0; r < 4; ++r) {
            const int row = row0 + i * 16 + r;
            float rs = 0.f;
#pragma unroll
            for (int j = 0; j < 2; ++j) {
                const int col = col0 + j * 16;
                // no max-subtraction: sims ~ +-0.3, exp safe; shift cancels.
                float e = (row == col) ? 0.f : __expf(acc[i][j][r]);
                acc[i][j][r] = e;
                rs += e;
                E[(long)row * N + col] = f2bf(e);
            }
#pragma unroll
            for (int off = 1; off < 16; off <<= 1) rs += __shfl_xor(rs, off);
            if (l15 == 0) atomicAdd(rowsum + row, rs);
        }
    }

    if (!diag) {
        // column sums -> row sums of the mirror tile
#pragma unroll
        for (int j = 0; j < 2; ++j) {
            float cs = 0.f;
#pragma unroll
            for (int i = 0; i < 4; ++i)
#pragma unroll
                for (int r = 0; r < 4; ++r) cs += acc[i][j][r];
            cs += __shfl_xor(cs, 16);
            cs += __shfl_xor(cs, 32);
            if (q == 0) atomicAdd(rowsum + bn + wn * 32 + j * 16 + l15, cs);
        }

        // per-wave 32x64 transpose through swizzled LDS (aliases As/Bs)
        unsigned short* tb = (unsigned short*)smem + wave * 2048;  // 4 KB/wave
        __syncthreads();
#pragma unroll
        for (int i = 0; i < 4; ++i) {
            const int lr0 = i * 16 + q * 4;
            const int blk = lr0 >> 3;
            const int half = (lr0 >> 2) & 1;
#pragma unroll
            for (int j = 0; j < 2; ++j) {
                const int lc = j * 16 + l15;
                union { unsigned short u[4]; uint2 v2; } pk;
#pragma unroll
                for (int r = 0; r < 4; ++r) pk.u[r] = f2bf(acc[i][j][r]);
                *(uint2*)&tb[lc * 64 + 8 * (blk ^ (lc & 7)) + 4 * half] = pk.v2;
            }
        }
        __syncthreads();

        const int gr0 = lane >> 3;
        const int cb  = lane & 7;
#pragma unroll
        for (int p = 0; p < 4; ++p) {
            const int gr = p * 8 + gr0;
            uint4 v = *(const uint4*)&tb[gr * 64 + 8 * (cb ^ (gr & 7))];
            *(uint4*)&E[(long)(bn + wn * 32 + gr) * N + bm + wm * 64 + cb * 8] = v;
        }
    }
}

// ---------------------------------------------------------------------------
// Kernel 3 (gemm_pv): out = (E/rowsum) x^T -- unchanged R2-verified bf16 GEMM
// (875 TF, 0 conflicts, 1024 blocks) with 1/rowsum fused into the epilogue.
// ---------------------------------------------------------------------------
__global__ __launch_bounds__(256) void gemm_pv(const bf16* __restrict__ A,
                                               const bf16* __restrict__ B,
                                               float* __restrict__ C,
                                               const float* __restrict__ rowsum) {
    __shared__ bf16 As[BM * BK];
    __shared__ bf16 Bs[BN * BK];

    const int t    = threadIdx.x;
    const int lane = t & 63;
    const int wave = t >> 6;
    const int wm   = wave >> 1;
    const int wn   = wave & 1;
    const int bm   = blockIdx.y * BM;
    const int bn   = blockIdx.x * BN;

    floatx4 acc[4][4] = {};

    const int srow = t >> 3;
    const int skb  = (t & 7) ^ (srow & 7);
    const bf16* Ag = A + (long)(bm + srow) * N + skb * 8;
    const bf16* Bg = B + (long)(bn + srow) * N + skb * 8;
    bf16* Asl = As + t * 8;
    bf16* Bsl = Bs + t * 8;

    for (int k0 = 0; k0 < N; k0 += BK) {
#pragma unroll
        for (int i = 0; i < 4; ++i) {
            gld_lds16(Ag + (long)i * 32 * N + k0, Asl + i * 2048);
            gld_lds16(Bg + (long)i * 32 * N + k0, Bsl + i * 2048);
        }
        __syncthreads();

        const int l15 = lane & 15;
        const int l7  = lane & 7;
        const int q   = lane >> 4;
#pragma unroll
        for (int kk = 0; kk < BK; kk += 32) {
            const int kw = (kk >> 3) + q;
            const int sw = kw ^ l7;
            bfrag a[4], b[4];
#pragma unroll
            for (int i = 0; i < 4; ++i)
                a[i] = *(const bfrag*)&As[((wm * 64 + i * 16 + l15) * 8 + sw) * 8];
#pragma unroll
            for (int j = 0; j < 4; ++j)
                b[j] = *(const bfrag*)&Bs[((wn * 64 + j * 16 + l15) * 8 + sw) * 8];
#pragma unroll
            for (int i = 0; i < 4; ++i)
#pragma unroll
                for (int j = 0; j < 4; ++j)
                    acc[i][j] = __builtin_amdgcn_mfma_f32_16x16x32_bf16(
                        a[i], b[j], acc[i][j], 0, 0, 0);
        }
        __syncthreads();
    }

    const int col0 = bn + wn * 64 + (lane & 15);
    const int row0 = bm + wm * 64 + (lane >> 4) * 4;
#pragma unroll
    for (int i = 0; i < 4; ++i) {
#pragma unroll
        for (int r = 0; r < 4; ++r) {
            const int row = row0 + i * 16 + r;
            const float inv = 1.0f / rowsum[row];
#pragma unroll
            for (int j = 0; j < 4; ++j)
                C[(long)row * N + col0 + j * 16] = acc[i][j][r] * inv;
        }
    }
}

// ---------------------------------------------------------------------------
extern "C" void kernel_launch(void* const* d_in, const int* in_sizes, int n_in,
                              void* d_out, int out_size, void* d_ws, size_t ws_size,
                              hipStream_t stream) {
    const float* in = (const float*)d_in[0];
    float* out = (float*)d_out;

    // ws layout: [rowsum 16KB] [xb 32MB bf16] [E 32MB bf16].
    // x8 (16MB fp8) lives in d_out's first 16MB -- dead until gemm_pv's
    // final write, which happens after gemm_sym has consumed x8.
    float* rowsum = (float*)d_ws;
    bf16* xb = (bf16*)((char*)d_ws + 16384);
    unsigned short* E = (unsigned short*)((char*)d_ws + 16384 + (size_t)N * N * sizeof(bf16));
    uint8_t* x8 = (uint8_t*)d_out;

    cvt_scale<<<(N * (long)N) / (256 * 8), 256, 0, stream>>>(
        in, (unsigned short*)xb, x8, rowsum);

    // E = exp(mask(x x^T)) via 528 triangular fp8 tiles (32 K-iterations)
    gemm_sym<<<528, 512, 0, stream>>>(x8, E, rowsum);
    // out = (E / rowsum) x^T
    dim3 grid(N / BN, N / BM);
    gemm_pv<<<grid, 256, 0, stream>>>((const bf16*)E, xb, out, rowsum);
}